// Round 5
// baseline (189.337 us; speedup 1.0000x reference)
//
#include <hip/hip_runtime.h>

using half8 = __attribute__((ext_vector_type(8))) _Float16;
using f32x4 = __attribute__((ext_vector_type(4))) float;

#define Lc 4096
#define Ec 64
#define Mc 64
#define BHc 128

// 2*pi/4096
#define TWO_PI_OVER_L 1.5339807878856412e-3f

// ---------------------------------------------------------------------------
// Twiddle tables, both coalesced:
//   Tt[m2][l]  f16, m2 in [0,128): rows 0..63 = cos(th), rows 64..127 = -sin(th)
//   UL[l][m2]  f16: cols 0..63 = cos(th), cols 64..127 = +sin(th)
// th = 2*pi*k_m*l/L
// ---------------------------------------------------------------------------
__global__ __launch_bounds__(256) void twid_k(const int* __restrict__ idx,
                                              _Float16* __restrict__ Tt,
                                              _Float16* __restrict__ UL) {
    int id = blockIdx.x * 256 + threadIdx.x;   // 0 .. 524287
    {   // UL pass: l = id>>7, m2 = id&127  (coalesced in m2)
        int l = id >> 7, m2 = id & 127, m = m2 & 63;
        int k = idx[m];
        int ph = (k * l) & (Lc - 1);
        float s, c;
        sincosf((float)ph * TWO_PI_OVER_L, &s, &c);
        UL[id] = (_Float16)((m2 >= 64) ? s : c);
    }
    {   // Tt pass: m2 = id>>12, l = id&4095  (coalesced in l)
        int m2 = id >> 12, l = id & 4095, m = m2 & 63;
        int k = idx[m];
        int ph = (k * l) & (Lc - 1);
        float s, c;
        sincosf((float)ph * TWO_PI_OVER_L, &s, &c);
        Tt[id] = (_Float16)((m2 >= 64) ? -s : c);
    }
}

// ---------------------------------------------------------------------------
// Transpose+convert: x[bh][l][e] f32 -> xT[bh][e][l] f16.
// grid (BHc, Lc/64), 256 thr. 64l x 64e tile per block, one barrier.
// LDS u32[64][36]: row = e, col = l-pair (36 -> 16B-aligned uint4 rows,
// ~2-way write / conflict-free read).
// ---------------------------------------------------------------------------
__global__ __launch_bounds__(256) void tr_k(const float* __restrict__ x,
                                            _Float16* __restrict__ xT) {
    __shared__ unsigned int lds[64][36];
    int bh = blockIdx.x, l0 = blockIdx.y * 64;
    int tid = threadIdx.x;
    #pragma unroll
    for (int i = 0; i < 2; ++i) {
        int idx = i * 256 + tid;               // 0..511
        int lp = idx >> 4, c4 = idx & 15;      // l-pair, e-group
        const float* gp = x + ((size_t)(bh * Lc + l0 + 2 * lp)) * Ec + c4 * 4;
        float4 a = *(const float4*)gp;
        float4 b = *(const float4*)(gp + Ec);
        const float* pa = &a.x;
        const float* pb = &b.x;
        #pragma unroll
        for (int q = 0; q < 4; ++q) {
            unsigned short u0 = __builtin_bit_cast(unsigned short, (_Float16)pa[q]);
            unsigned short u1 = __builtin_bit_cast(unsigned short, (_Float16)pb[q]);
            lds[c4 * 4 + q][lp] = u0 | ((unsigned int)u1 << 16);
        }
    }
    __syncthreads();
    #pragma unroll
    for (int j = 0; j < 2; ++j) {
        int idx = j * 256 + tid;               // 0..511
        int e = idx >> 3, c = idx & 7;
        uint4 v = *(const uint4*)&lds[e][c * 4];
        *(uint4*)(xT + ((size_t)bh * 64 + e) * Lc + l0 + c * 8) = v;
    }
}

// ---------------------------------------------------------------------------
// Forward: selP[ch][bh][m2=128][e=64] = sum_{l in chunk} Tt[m2][l] * xT[e][l]
// grid (BHc, NCH), 256 thr (4 waves). Wave w owns m2 rows [32w, 32w+32),
// all 64 e. NO LDS, NO barriers: A (Tt) and B (xT) fragments are contiguous
// half8 global loads (wave covers full 64B lines), explicit 1-ahead register
// prefetch across the k-loop.
// MFMA mapping (16x16x32): A row=lane&15, k=(lane>>4)*8+i; B col=lane&15;
// D col=lane&15, row=(lane>>4)*4+reg.
// ---------------------------------------------------------------------------
template<int NCH>
__global__ __launch_bounds__(256) void fwd_k(const _Float16* __restrict__ xT,
                                             const _Float16* __restrict__ Tt,
                                             float* __restrict__ selP) {
    constexpr int CH = Lc / NCH;
    constexpr int NS = CH / 32;                // k-steps of 32
    int bh = blockIdx.x, ch = blockIdx.y;
    int tid = threadIdx.x, lane = tid & 63, w = tid >> 6;
    int lo16 = lane & 15, kg = lane >> 4;

    const _Float16* tp = Tt + (size_t)(w * 32 + lo16) * Lc + ch * CH + kg * 8;
    const _Float16* xp = xT + (size_t)bh * 64 * Lc + (size_t)lo16 * Lc + ch * CH + kg * 8;

    half8 A0 = *(const half8*)(tp);
    half8 A1 = *(const half8*)(tp + (size_t)16 * Lc);
    half8 B0 = *(const half8*)(xp);
    half8 B1 = *(const half8*)(xp + (size_t)16 * Lc);
    half8 B2 = *(const half8*)(xp + (size_t)32 * Lc);
    half8 B3 = *(const half8*)(xp + (size_t)48 * Lc);

    f32x4 acc[2][4] = {};
    for (int s = 0; s < NS; ++s) {
        half8 a0 = A0, a1 = A1, b0 = B0, b1 = B1, b2 = B2, b3 = B3;
        if (s + 1 < NS) {                      // prefetch next k-step
            int o = (s + 1) * 32;
            A0 = *(const half8*)(tp + o);
            A1 = *(const half8*)(tp + (size_t)16 * Lc + o);
            B0 = *(const half8*)(xp + o);
            B1 = *(const half8*)(xp + (size_t)16 * Lc + o);
            B2 = *(const half8*)(xp + (size_t)32 * Lc + o);
            B3 = *(const half8*)(xp + (size_t)48 * Lc + o);
        }
        acc[0][0] = __builtin_amdgcn_mfma_f32_16x16x32_f16(a0, b0, acc[0][0], 0, 0, 0);
        acc[1][0] = __builtin_amdgcn_mfma_f32_16x16x32_f16(a1, b0, acc[1][0], 0, 0, 0);
        acc[0][1] = __builtin_amdgcn_mfma_f32_16x16x32_f16(a0, b1, acc[0][1], 0, 0, 0);
        acc[1][1] = __builtin_amdgcn_mfma_f32_16x16x32_f16(a1, b1, acc[1][1], 0, 0, 0);
        acc[0][2] = __builtin_amdgcn_mfma_f32_16x16x32_f16(a0, b2, acc[0][2], 0, 0, 0);
        acc[1][2] = __builtin_amdgcn_mfma_f32_16x16x32_f16(a1, b2, acc[1][2], 0, 0, 0);
        acc[0][3] = __builtin_amdgcn_mfma_f32_16x16x32_f16(a0, b3, acc[0][3], 0, 0, 0);
        acc[1][3] = __builtin_amdgcn_mfma_f32_16x16x32_f16(a1, b3, acc[1][3], 0, 0, 0);
    }
    float* op = selP + (size_t)(ch * BHc + bh) * (128 * Ec);
    #pragma unroll
    for (int a = 0; a < 2; ++a)
        #pragma unroll
        for (int j = 0; j < 4; ++j)
            #pragma unroll
            for (int r = 0; r < 4; ++r) {
                int m2 = w * 32 + a * 16 + kg * 4 + r;
                int e  = 16 * j + lo16;
                op[m2 * Ec + e] = acc[a][j][r];
            }
}

// ---------------------------------------------------------------------------
// Mix: reduce K-partials, apply complex weight einsum, fold irfft scale.
// Vt[bh][o=64][m2=128] f16: cols 0..63 = s*Re(out_sel), 64..127 = -s*Im(out_sel)
// grid (BHc, 2) o-halves, 256 thr. Thread owns 4 o x 2 m.
// ---------------------------------------------------------------------------
__global__ __launch_bounds__(256) void mix_k(const float* __restrict__ selP,
                                             const float* __restrict__ wgt,
                                             const int* __restrict__ idx,
                                             _Float16* __restrict__ Vt, int nch) {
    __shared__ float sel_s[128 * 65];          // [m2][65] padded, 33.3KB
    int bh = blockIdx.x, oh = blockIdx.y;
    int tid = threadIdx.x;
    #pragma unroll
    for (int i = 0; i < 8; ++i) {
        int f4 = i * 256 + tid;                // 2048 float4 = 8192 floats
        float4 a = make_float4(0.f, 0.f, 0.f, 0.f);
        for (int chn = 0; chn < nch; ++chn) {
            float4 v = *((const float4*)(selP + (size_t)(chn * BHc + bh) * 8192) + f4);
            a.x += v.x; a.y += v.y; a.z += v.z; a.w += v.w;
        }
        int m2 = f4 >> 4, e4 = (f4 & 15) * 4;
        float* dst = &sel_s[m2 * 65 + e4];
        dst[0] = a.x; dst[1] = a.y; dst[2] = a.z; dst[3] = a.w;
    }
    __syncthreads();
    int og = tid & 7, mg = tid >> 3;
    int o0 = oh * 32 + og * 4;
    int m0 = mg * 2;
    float rR[4][2] = {{0}}, rI[4][2] = {{0}};
    for (int e = 0; e < Ec; ++e) {
        float sr0 = sel_s[m0 * 65 + e];
        float sr1 = sel_s[(m0 + 1) * 65 + e];
        float si0 = sel_s[(64 + m0) * 65 + e];
        float si1 = sel_s[(64 + m0 + 1) * 65 + e];
        #pragma unroll
        for (int i = 0; i < 4; ++i) {
            const float4* wp = (const float4*)&wgt[(((size_t)e * Ec + (o0 + i)) * Mc + m0) * 2];
            float4 wv = *wp;   // wR[m0], wI[m0], wR[m0+1], wI[m0+1]
            rR[i][0] += sr0 * wv.x - si0 * wv.y;
            rI[i][0] += sr0 * wv.y + si0 * wv.x;
            rR[i][1] += sr1 * wv.z - si1 * wv.w;
            rI[i][1] += sr1 * wv.w + si1 * wv.z;
        }
    }
    float s0 = (idx[m0] == 0 ? 1.0f : 2.0f) / (float)Lc;
    float s1 = (idx[m0 + 1] == 0 ? 1.0f : 2.0f) / (float)Lc;
    #pragma unroll
    for (int i = 0; i < 4; ++i) {
        _Float16* vp = Vt + ((size_t)bh * 64 + o0 + i) * 128;
        unsigned short r0 = __builtin_bit_cast(unsigned short, (_Float16)(rR[i][0] * s0));
        unsigned short r1 = __builtin_bit_cast(unsigned short, (_Float16)(rR[i][1] * s1));
        unsigned short i0 = __builtin_bit_cast(unsigned short, (_Float16)(-rI[i][0] * s0));
        unsigned short i1 = __builtin_bit_cast(unsigned short, (_Float16)(-rI[i][1] * s1));
        *(unsigned int*)&vp[m0]      = r0 | ((unsigned int)r1 << 16);
        *(unsigned int*)&vp[64 + m0] = i0 | ((unsigned int)i1 << 16);
    }
}

// ---------------------------------------------------------------------------
// Inverse: out[bh][l][o] = sum_{m2} UL[l][m2] * V[m2][o]
// grid (BHc, 16), 256 thr. Wave w owns l rows [64w, 64w+64) of a 256-l block.
// NO LDS, NO barriers: Vt (16KB/bh) is L2-resident; fully unrolled k-loop so
// all 32 fragment loads hoist to the top.
// ---------------------------------------------------------------------------
__global__ __launch_bounds__(256) void inv_k(const _Float16* __restrict__ UL,
                                             const _Float16* __restrict__ Vt,
                                             float* __restrict__ out) {
    int bh = blockIdx.x, lb = blockIdx.y;
    int tid = threadIdx.x, lane = tid & 63, w = tid >> 6;
    int lo16 = lane & 15, kg = lane >> 4;
    int lt0 = lb * 256 + w * 64;
    const _Float16* up = UL + (size_t)(lt0 + lo16) * 128 + kg * 8;
    const _Float16* vp = Vt + (size_t)bh * 8192 + (size_t)lo16 * 128 + kg * 8;
    f32x4 acc[4][4] = {};
    #pragma unroll
    for (int ks = 0; ks < 4; ++ks) {
        half8 Af[4], Bf[4];
        #pragma unroll
        for (int a = 0; a < 4; ++a)
            Af[a] = *(const half8*)(up + (size_t)a * 16 * 128 + ks * 32);
        #pragma unroll
        for (int j = 0; j < 4; ++j)
            Bf[j] = *(const half8*)(vp + (size_t)j * 16 * 128 + ks * 32);
        #pragma unroll
        for (int j = 0; j < 4; ++j)
            #pragma unroll
            for (int a = 0; a < 4; ++a)
                acc[a][j] = __builtin_amdgcn_mfma_f32_16x16x32_f16(Af[a], Bf[j], acc[a][j], 0, 0, 0);
    }
    float* op = out + ((size_t)bh * Lc + lt0) * Ec;
    #pragma unroll
    for (int a = 0; a < 4; ++a)
        #pragma unroll
        for (int j = 0; j < 4; ++j)
            #pragma unroll
            for (int r = 0; r < 4; ++r) {
                int ll = a * 16 + kg * 4 + r;
                int o  = 16 * j + lo16;
                op[ll * Ec + o] = acc[a][j][r];
            }
}

// ---------------------------------------------------------------------------
extern "C" void kernel_launch(void* const* d_in, const int* in_sizes, int n_in,
                              void* d_out, int out_size, void* d_ws, size_t ws_size,
                              hipStream_t stream) {
    const float* x   = (const float*)d_in[0];
    const float* wgt = (const float*)d_in[1];
    const int*   idx = (const int*)d_in[2];
    float* out = (float*)d_out;

    // ws layout: selP (nch*4MB) | Tt (1MB) | UL (1MB) | Vt (2MB) | xT (67MB)
    size_t tables = (2ull * 128 * Lc + (size_t)BHc * 8192) * 2;
    size_t xT_b   = (size_t)BHc * 64 * Lc * 2;
    size_t need8  = (size_t)8 * BHc * 8192 * 4 + tables + xT_b;
    int nch = (ws_size >= need8) ? 8 : 4;

    char* ws = (char*)d_ws;
    float*    selP = (float*)ws;
    _Float16* Tt   = (_Float16*)(ws + (size_t)nch * BHc * 8192 * 4);
    _Float16* UL   = Tt + (size_t)128 * Lc;
    _Float16* Vt   = UL + (size_t)Lc * 128;
    _Float16* xT   = Vt + (size_t)BHc * 8192;

    twid_k<<<2048, 256, 0, stream>>>(idx, Tt, UL);
    tr_k<<<dim3(BHc, Lc / 64), 256, 0, stream>>>(x, xT);
    if (nch == 8)
        fwd_k<8><<<dim3(BHc, 8), 256, 0, stream>>>(xT, Tt, selP);
    else
        fwd_k<4><<<dim3(BHc, 4), 256, 0, stream>>>(xT, Tt, selP);
    mix_k<<<dim3(BHc, 2), 256, 0, stream>>>(selP, wgt, idx, Vt, nch);
    inv_k<<<dim3(BHc, 16), 256, 0, stream>>>(UL, Vt, out);
}